// Round 9
// baseline (636.178 us; speedup 1.0000x reference)
//
#include <hip/hip_runtime.h>
#include <hip/hip_cooperative_groups.h>
#include <stdint.h>
#include <math.h>

namespace cg = cooperative_groups;

typedef unsigned long long u64;
typedef uint32_t u32;

#define BATCH   262144
#define DIM     120
#define NBLKM   1024      // mega: blocks of 256 rows
#define CH      8         // columns per register chunk
#define NBLK1   2048      // fallback K1/K2 blocks
#define NPART   4096
#define NBLK3   1024

// Bit permutation (x and w MUST match): element c -> plane (c&3), bit (c>>2).
// p0 = plane0 | plane1<<30 ; p1 = plane2 | plane3<<30 (60 bits used).

// ---------------- workspace layout (bytes) ----------------
#define WS_XBITS   0              // fallback only: u64[BATCH*4]
#define WS_WBITS   8388608
#define WS_LWQ     8392704
#define WS_META    8393216        // u32[256]
#define WS_HS      8394240        // mega: hP u32[120*2048] / fallback hS
#define WS_HS2     10360320      // mega: h2P / fallback hS2
#define WS_SS      12326400      // sP f32[120*4096]
#define WS_SS2     14292480      // s2P
#define WS_BN2C    16258560      // f32[256]
#define WS_OQ      16259584      // fallback only
#define WS_OACC    17308160
#define WS_OP      17308224      // u32[1024*4]
#define WS_TOTAL   17324624

__device__ __forceinline__ u32 hq_from_bits(u64 p0, u64 p1, u64 z0, u64 z1,
                                            u64 q0, u64 q1, u64 y0, u64 y1,
                                            bool hasY, bool hasZ) {
    u32 hq = (u32)(__popcll(p0 & q0) + __popcll(p1 & q1)) << 2;
    if (hasY)
        hq += 2u * (u32)(__popcll(p0 & y0) + __popcll(p1 & y1))
            + (u32)(__popcll(z0 & y0) + __popcll(z1 & y1));
    if (hasZ)
        hq += 2u * (u32)(__popcll(z0 & q0) + __popcll(z1 & q1));
    return hq;   // == 4 * h, exact integer in [0, 480]
}

__device__ __forceinline__ void proc_col(u64 p0, u64 p1, u64 q0, u64 q1,
                                         u64 mw, u32& oq) {
    u32 hq = ((u32)(__popcll(p0 & q0) + __popcll(p1 & q1))) << 2;
    u32 m  = (u32)mw;
    u32 lw = (u32)(mw >> 32);
    u32 ge = (u32)(hq >= (m & 511u)) + (u32)(hq >= ((m >> 9) & 511u));
    u32 hb2 = (m & (1u << 18)) ? 2u - ge : ge;
    oq += hb2 * lw;
}

// ================= MEGA: whole pipeline, one cooperative launch ============
__global__ __launch_bounds__(256, 4) void mega(
        const float* __restrict__ x, const float* __restrict__ w,
        const float* __restrict__ g2, const float* __restrict__ b2,
        const float* __restrict__ g1, const float* __restrict__ b1,
        const float* __restrict__ lw, float* __restrict__ out,
        u32* hP, u32* h2P, float* sP, float* s2P,
        float* bn2c, u32* meta, u32* oP) {
    cg::grid_group grid = cg::this_grid();
    __shared__ __align__(16) u64 lb[256][4];   // row bits, persists all phases
    __shared__ __align__(16) u64 sw[128][4];   // w bits q0,q1,y0,y1
    __shared__ __align__(16) u64 sq0[128], sq1[128], smw[128];
    __shared__ u32 swf[4];
    __shared__ u32 ru32[4][4];
    __shared__ u64 ru64[4][4];
    __shared__ double rdbl[2][4];
    __shared__ float sc2[2];
    __shared__ u32 cnt[3];
    __shared__ u32 sfl[2];
    __shared__ float sfin[4];

    const int tid = threadIdx.x, lane = tid & 63, wv = tid >> 6;
    const int l = lane & 31, h32 = lane >> 5;
    const int bid = blockIdx.x;
    const u64 M = 0x3FFFFFFFull;

    // ---- Phase 0a: pack conv_w per block (L2-resident redundant read) ----
    u64 accy = 0;
    for (int jj = wv * 2; jj < DIM; jj += 8) {
        int j = jj + h32;
        float4 v = make_float4(-1.f, -1.f, -1.f, -1.f);
        if (l < 30) v = *(const float4*)(w + (size_t)j * DIM + l * 4);
        u64 m0 = __ballot(v.x > 0.f), m1 = __ballot(v.y > 0.f);
        u64 m2 = __ballot(v.z > 0.f), m3 = __ballot(v.w > 0.f);
        u64 n0 = __ballot(v.x == 0.f), n1 = __ballot(v.y == 0.f);
        u64 n2 = __ballot(v.z == 0.f), n3 = __ballot(v.w == 0.f);
        accy |= (n0 | n1 | n2 | n3);
        if (l == 0) {
            u32 sh = h32 ? 32 : 0;
            sw[j][0] = ((m0>>sh)&M) | (((m1>>sh)&M) << 30);
            sw[j][1] = ((m2>>sh)&M) | (((m3>>sh)&M) << 30);
            sw[j][2] = ((n0>>sh)&M) | (((n1>>sh)&M) << 30);
            sw[j][3] = ((n2>>sh)&M) | (((n3>>sh)&M) << 30);
        }
    }
    if (tid >= 120 && tid < 128) { sw[tid][0]=0; sw[tid][1]=0; sw[tid][2]=0; sw[tid][3]=0; }
    u32 af = __any(accy != 0) ? 1u : 0u;
    if (lane == 0) swf[wv] = af;

    // ---- Phase 0b: pack this block's 256 x-rows ----
    for (int rr = 0; rr < 32; ++rr) {
        int r = rr * 8 + wv * 2 + h32;
        float4 v = make_float4(-1.f, -1.f, -1.f, -1.f);
        if (l < 30) v = *(const float4*)(x + ((size_t)bid * 256 + r) * DIM + l * 4);
        u64 m0 = __ballot(v.x > 0.f), m1 = __ballot(v.y > 0.f);
        u64 m2 = __ballot(v.z > 0.f), m3 = __ballot(v.w > 0.f);
        u64 n0 = __ballot(v.x == 0.f), n1 = __ballot(v.y == 0.f);
        u64 n2 = __ballot(v.z == 0.f), n3 = __ballot(v.w == 0.f);
        if (l == 0) {
            u32 sh = h32 ? 32 : 0;
            lb[r][0] = ((m0>>sh)&M) | (((m1>>sh)&M) << 30);
            lb[r][1] = ((m2>>sh)&M) | (((m3>>sh)&M) << 30);
            lb[r][2] = ((n0>>sh)&M) | (((n1>>sh)&M) << 30);
            lb[r][3] = ((n2>>sh)&M) | (((n3>>sh)&M) << 30);
        }
    }
    __syncthreads();
    const bool gyf = (swf[0] | swf[1] | swf[2] | swf[3]) != 0;
    const u64 p0 = lb[tid][0], p1 = lb[tid][1];
    const u64 zz0 = lb[tid][2], zz1 = lb[tid][3];

    // ---- Phase 0c: integer h-stats (thread <-> column, 128 rows) ----
    {
        int j = tid & 127, hh = tid >> 7;
        if (j < DIM) {
            u64 q0 = sw[j][0], q1 = sw[j][1], y0 = sw[j][2], y1 = sw[j][3];
            bool hasY = (y0 | y1) != 0;
            u32 S = 0, S2 = 0;
            int r0 = hh * 128;
            for (int r = r0; r < r0 + 128; ++r) {
                u64 z0 = lb[r][2], z1 = lb[r][3];
                u32 hq = hq_from_bits(lb[r][0], lb[r][1], z0, z1,
                                      q0, q1, y0, y1, hasY, (z0 | z1) != 0);
                S += hq; S2 += hq * hq;
            }
            hP[j*2048 + bid*2 + hh] = S;
            h2P[j*2048 + bid*2 + hh] = S2;
        }
    }
    grid.sync();

    // ---- Phase 1: BN2 constants (blocks 0..119) ----
    if (bid < DIM) {
        int j = bid;
        u32 s = 0; u64 s2 = 0;
        for (int k = tid; k < 2048; k += 256) { s += hP[j*2048+k]; s2 += (u64)h2P[j*2048+k]; }
        for (int off = 32; off; off >>= 1) { s += __shfl_down(s, off, 64); s2 += __shfl_down(s2, off, 64); }
        if (lane == 0) { ru32[0][wv] = s; ru64[0][wv] = s2; }
        __syncthreads();
        if (tid == 0) {
            u32 S = ru32[0][0]+ru32[0][1]+ru32[0][2]+ru32[0][3];
            u64 S2 = ru64[0][0]+ru64[0][1]+ru64[0][2]+ru64[0][3];
            double m2 = (double)S * 0.25 / (double)BATCH;
            double e2 = (double)S2 * 0.0625 / (double)BATCH;
            double v2 = e2 - m2 * m2;
            float rs = (float)(1.0 / sqrt(v2 + 1e-5));
            float c1 = rs * g2[j];
            float c0 = fmaf(-(float)m2, c1, b2[j]);
            bn2c[j] = c1 * 0.25f; bn2c[128 + j] = c0;
        }
    }
    grid.sync();

    // ---- Phase 2: softsign stats (bit-identical 64-row grouping) ----
    {
        int j = tid & 127, hh = tid >> 7;
        if (j < DIM) {
            u64 q0 = sw[j][0], q1 = sw[j][1], y0 = sw[j][2], y1 = sw[j][3];
            bool hasY = (y0 | y1) != 0;
            float c1q = bn2c[j], c0 = bn2c[128 + j];
            #pragma unroll
            for (int c = 0; c < 2; ++c) {
                float SsA = 0.f, Ss2A = 0.f, SsB = 0.f, Ss2B = 0.f;
                int r0 = hh * 128 + c * 64;
                for (int r = r0; r < r0 + 64; r += 2) {
                    u64 z0 = lb[r][2], z1 = lb[r][3];
                    u32 hqa = hq_from_bits(lb[r][0], lb[r][1], z0, z1,
                                           q0, q1, y0, y1, hasY, (z0 | z1) != 0);
                    u64 w0 = lb[r+1][2], w1 = lb[r+1][3];
                    u32 hqb = hq_from_bits(lb[r+1][0], lb[r+1][1], w0, w1,
                                           q0, q1, y0, y1, hasY, (w0 | w1) != 0);
                    float za = fmaf((float)hqa, c1q, c0);
                    float sa = za * __builtin_amdgcn_rcpf(1.f + fabsf(za));
                    SsA += sa; Ss2A = fmaf(sa, sa, Ss2A);
                    float zb = fmaf((float)hqb, c1q, c0);
                    float sb = zb * __builtin_amdgcn_rcpf(1.f + fabsf(zb));
                    SsB += sb; Ss2B = fmaf(sb, sb, Ss2B);
                }
                int pidx = j*4096 + bid*4 + hh*2 + c;
                sP[pidx] = SsA + SsB; s2P[pidx] = Ss2A + Ss2B;
            }
        }
    }
    grid.sync();

    // ---- Phase 3: BN1 + thresholds + meta (blocks 0..119; pad 120..127) ----
    if (bid < DIM) {
        int j = bid;
        double s = 0.0, s2 = 0.0;
        for (int k = tid; k < 4096; k += 256) { s += (double)sP[j*4096+k]; s2 += (double)s2P[j*4096+k]; }
        for (int off = 32; off; off >>= 1) { s += __shfl_down(s, off, 64); s2 += __shfl_down(s2, off, 64); }
        if (lane == 0) { rdbl[0][wv] = s; rdbl[1][wv] = s2; }
        if (tid < 3) cnt[tid] = 0;
        __syncthreads();
        if (tid == 0) {
            double S = rdbl[0][0]+rdbl[0][1]+rdbl[0][2]+rdbl[0][3];
            double S2 = rdbl[1][0]+rdbl[1][1]+rdbl[1][2]+rdbl[1][3];
            double m1 = S / (double)BATCH;
            double v1 = S2 / (double)BATCH - m1 * m1;
            float rs = (float)(1.0 / sqrt(v1 + 1e-5));
            float d1 = rs * g1[j];
            float d0 = fmaf(-(float)m1, d1, b1[j]);
            sc2[0] = d1; sc2[1] = d0;
        }
        __syncthreads();
        float c1q = bn2c[j], c0 = bn2c[128 + j];
        float d1 = sc2[0], d0 = sc2[1];
        for (int hq = tid; hq < 481; hq += 256) {
            float z = fmaf((float)hq, c1q, c0);
            float sv = z * __builtin_amdgcn_rcpf(1.f + fabsf(z));
            float h1 = fmaf(sv, d1, d0);
            u32 hb2 = h1 > 0.f ? 2u : (h1 == 0.f ? 1u : 0u);
            atomicAdd(&cnt[hb2], 1u);
            if (hq == 0)   sfl[0] = hb2;
            if (hq == 480) sfl[1] = hb2;
        }
        __syncthreads();
        if (tid == 0) {
            u32 n0 = cnt[0], n1 = cnt[1], n2 = cnt[2];
            u32 dec = (sfl[1] < sfl[0]) ? 1u : 0u;
            u32 A = dec ? n2 : n0;
            u32 B = A + n1;
            float w0 = lw[j], w1 = lw[DIM + j];
            u32 l0 = w0 > 0.f ? 2u : (w0 == 0.f ? 1u : 0u);
            u32 l1 = w1 > 0.f ? 2u : (w1 == 0.f ? 1u : 0u);
            meta[2*j]   = A | (B << 9) | (dec << 18);
            meta[2*j+1] = l0 | (l1 << 16);
        }
    } else if (bid < 128) {
        if (tid == 0) { meta[2*bid] = 0; meta[2*bid+1] = 0; }
    }
    grid.sync();

    // ---- Phase 4: output pass (row bits in registers, chunked columns) ----
    if (tid < 128) {
        sq0[tid] = sw[tid][0]; sq1[tid] = sw[tid][1];
        smw[tid] = (u64)meta[2*tid] | ((u64)meta[2*tid+1] << 32);
    }
    __syncthreads();
    u32 oq = 0;
    for (int c = 0; c < DIM; c += CH) {
        ulonglong2 A[CH/2], B[CH/2], Mw[CH/2];
        #pragma unroll
        for (int t = 0; t < CH/2; ++t) {
            A[t]  = *(const ulonglong2*)&sq0[c + 2*t];
            B[t]  = *(const ulonglong2*)&sq1[c + 2*t];
            Mw[t] = *(const ulonglong2*)&smw[c + 2*t];
        }
        #pragma unroll
        for (int t = 0; t < CH/2; ++t) {
            proc_col(p0, p1, A[t].x, B[t].x, Mw[t].x, oq);
            proc_col(p0, p1, A[t].y, B[t].y, Mw[t].y, oq);
        }
    }
    {
        bool slow = gyf | ((zz0 | zz1) != 0);
        if (__any(slow)) {
            if (slow) {      // exact recompute, expected ~2 rows per batch
                oq = 0;
                for (int j = 0; j < DIM; ++j) {
                    u64 y0 = sw[j][2], y1 = sw[j][3];
                    u32 hq = hq_from_bits(p0, p1, zz0, zz1, sq0[j], sq1[j], y0, y1,
                                          (y0 | y1) != 0, (zz0 | zz1) != 0);
                    u64 mw = smw[j];
                    u32 m = (u32)mw, lwp = (u32)(mw >> 32);
                    u32 ge = (u32)(hq >= (m & 511u)) + (u32)(hq >= ((m >> 9) & 511u));
                    oq += ((m & (1u << 18)) ? 2u - ge : ge) * lwp;
                }
            }
        }
        u32 o0 = oq & 0xffffu, o1 = oq >> 16;
        u32 a = o0, b = o1, c2 = o0*o0, d2 = o1*o1;
        for (int off = 32; off; off >>= 1) {
            a += __shfl_down(a, off, 64);  b += __shfl_down(b, off, 64);
            c2 += __shfl_down(c2, off, 64); d2 += __shfl_down(d2, off, 64);
        }
        if (lane == 0) { ru32[0][wv]=a; ru32[1][wv]=b; ru32[2][wv]=c2; ru32[3][wv]=d2; }
        __syncthreads();
        if (tid == 0) {
            u32* dst = oP + (size_t)bid * 4;
            dst[0] = ru32[0][0]+ru32[0][1]+ru32[0][2]+ru32[0][3];
            dst[1] = ru32[1][0]+ru32[1][1]+ru32[1][2]+ru32[1][3];
            dst[2] = ru32[2][0]+ru32[2][1]+ru32[2][2]+ru32[2][3];
            dst[3] = ru32[3][0]+ru32[3][1]+ru32[3][2]+ru32[3][3];
        }
    }
    grid.sync();

    // ---- Phase 5: output BN + log_softmax (oq still in register) ----
    {
        u64 a = 0, b = 0, c2 = 0, d2 = 0;
        for (int k = tid; k < NBLKM; k += 256) {
            uint4 p = ((const uint4*)oP)[k];
            a += p.x; b += p.y; c2 += p.z; d2 += p.w;
        }
        for (int off = 32; off; off >>= 1) {
            a += __shfl_down(a, off, 64);  b += __shfl_down(b, off, 64);
            c2 += __shfl_down(c2, off, 64); d2 += __shfl_down(d2, off, 64);
        }
        if (lane == 0) { ru64[0][wv]=a; ru64[1][wv]=b; ru64[2][wv]=c2; ru64[3][wv]=d2; }
        __syncthreads();
        if (tid < 2) {
            u64 S  = (tid == 0) ? ru64[0][0]+ru64[0][1]+ru64[0][2]+ru64[0][3]
                                : ru64[1][0]+ru64[1][1]+ru64[1][2]+ru64[1][3];
            u64 S2 = (tid == 0) ? ru64[2][0]+ru64[2][1]+ru64[2][2]+ru64[2][3]
                                : ru64[3][0]+ru64[3][1]+ru64[3][2]+ru64[3][3];
            double av = (double)S * 0.25 / (double)BATCH;
            double e2 = (double)S2 * 0.0625 / (double)BATCH;
            double vo = e2 - av * av;
            sfin[tid]     = (float)av;
            sfin[2 + tid] = (float)(1.0 / sqrt(vo + 1e-5));
        }
        __syncthreads();
        size_t row = (size_t)bid * 256 + tid;
        float o0 = ((float)(oq & 0xffffu) * 0.25f - sfin[0]) * sfin[2];
        float o1 = ((float)(oq >> 16)     * 0.25f - sfin[1]) * sfin[3];
        float m = fmaxf(o0, o1);
        float l0f = o0 - m, l1f = o1 - m;
        float ls = logf(expf(l0f) + expf(l1f));
        ((float2*)out)[row] = make_float2(l0f - ls, l1f - ls);
    }
}

// ====================== FALLBACK: round-8 7-kernel path ====================
__global__ __launch_bounds__(256) void kw_pack(
        const float* __restrict__ w, const float* __restrict__ lw,
        u64* __restrict__ wbits, u32* __restrict__ lwq, u32* __restrict__ oaccz) {
    int tid = threadIdx.x, lane = tid & 63, wv = tid >> 6;
    int l = lane & 31, h = lane >> 5;
    if (tid < 12) oaccz[tid] = 0;
    __syncthreads();
    u64 accy = 0;
    const u64 M = 0x3FFFFFFFull;
    for (int jj = wv * 2; jj < DIM; jj += 8) {
        int j = jj + h;
        float4 v = make_float4(-1.f, -1.f, -1.f, -1.f);
        if (l < 30) v = *(const float4*)(w + (size_t)j * DIM + l * 4);
        u64 m0 = __ballot(v.x > 0.f), m1 = __ballot(v.y > 0.f);
        u64 m2 = __ballot(v.z > 0.f), m3 = __ballot(v.w > 0.f);
        u64 n0 = __ballot(v.x == 0.f), n1 = __ballot(v.y == 0.f);
        u64 n2 = __ballot(v.z == 0.f), n3 = __ballot(v.w == 0.f);
        accy |= (n0 | n1 | n2 | n3);
        if (l == 0) {
            u32 sh = h ? 32 : 0;
            wbits[j*4+0] = ((m0>>sh)&M) | (((m1>>sh)&M) << 30);
            wbits[j*4+1] = ((m2>>sh)&M) | (((m3>>sh)&M) << 30);
            wbits[j*4+2] = ((n0>>sh)&M) | (((n1>>sh)&M) << 30);
            wbits[j*4+3] = ((n2>>sh)&M) | (((n3>>sh)&M) << 30);
        }
    }
    if (lane == 0 && accy) atomicOr(&oaccz[8], 1u);
    if (tid >= 120 && tid < 128) {
        wbits[tid*4+0] = 0; wbits[tid*4+1] = 0;
        wbits[tid*4+2] = 0; wbits[tid*4+3] = 0;
    }
    if (tid < DIM) {
        float w0 = lw[tid], w1 = lw[DIM + tid];
        u32 l0 = w0 > 0.f ? 2u : (w0 == 0.f ? 1u : 0u);
        u32 l1 = w1 > 0.f ? 2u : (w1 == 0.f ? 1u : 0u);
        lwq[tid] = l0 | (l1 << 16);
    }
}

__global__ __launch_bounds__(256) void k1_pack_hstats(
        const float* __restrict__ x, const u64* __restrict__ wbits,
        u64* __restrict__ xbits, u32* __restrict__ hS, u32* __restrict__ hS2) {
    __shared__ u64 lb[128][4];
    int tid = threadIdx.x, lane = tid & 63, wave = tid >> 6;
    int l = lane & 31, h = lane >> 5;
    size_t rowbase = (size_t)blockIdx.x * 128;
    const u64 M = 0x3FFFFFFFull;
    for (int rr = 0; rr < 16; ++rr) {
        int r = rr * 8 + wave * 2 + h;
        float4 v = make_float4(-1.f, -1.f, -1.f, -1.f);
        if (l < 30) v = *(const float4*)(x + (rowbase + r) * (size_t)DIM + l * 4);
        u64 m0 = __ballot(v.x > 0.f), m1 = __ballot(v.y > 0.f);
        u64 m2 = __ballot(v.z > 0.f), m3 = __ballot(v.w > 0.f);
        u64 n0 = __ballot(v.x == 0.f), n1 = __ballot(v.y == 0.f);
        u64 n2 = __ballot(v.z == 0.f), n3 = __ballot(v.w == 0.f);
        if (l == 0) {
            u32 sh = h ? 32 : 0;
            lb[r][0] = ((m0>>sh)&M) | (((m1>>sh)&M) << 30);
            lb[r][1] = ((m2>>sh)&M) | (((m3>>sh)&M) << 30);
            lb[r][2] = ((n0>>sh)&M) | (((n1>>sh)&M) << 30);
            lb[r][3] = ((n2>>sh)&M) | (((n3>>sh)&M) << 30);
        }
    }
    __syncthreads();
    ((ulonglong2*)(xbits + (size_t)blockIdx.x * 512))[tid] =
        ((const ulonglong2*)&lb[0][0])[tid];
    int j = tid & 127, half = tid >> 7;
    if (j < DIM) {
        u64 q0 = wbits[j*4+0], q1 = wbits[j*4+1], y0 = wbits[j*4+2], y1 = wbits[j*4+3];
        bool hasY = (y0 | y1) != 0;
        u32 S = 0, S2 = 0;
        int r0 = half * 64;
        for (int r = r0; r < r0 + 64; ++r) {
            u64 z0 = lb[r][2], z1 = lb[r][3];
            u32 hq = hq_from_bits(lb[r][0], lb[r][1], z0, z1,
                                  q0, q1, y0, y1, hasY, (z0 | z1) != 0);
            S += hq; S2 += hq * hq;
        }
        int pidx = j * NPART + blockIdx.x * 2 + half;
        hS[pidx] = S; hS2[pidx] = S2;
    }
}

__global__ __launch_bounds__(256) void r1_hreduce(
        const u32* __restrict__ hS, const u32* __restrict__ hS2,
        const float* __restrict__ g2, const float* __restrict__ b2,
        float* __restrict__ bn2c) {
    int j = blockIdx.x, tid = threadIdx.x;
    u32 s = 0; u64 s2 = 0;
    for (int k = tid; k < NPART; k += 256) { s += hS[j*NPART+k]; s2 += (u64)hS2[j*NPART+k]; }
    for (int off = 32; off; off >>= 1) { s += __shfl_down(s, off, 64); s2 += __shfl_down(s2, off, 64); }
    __shared__ u32 as_[4]; __shared__ u64 as2_[4];
    int lane = tid & 63, wave = tid >> 6;
    if (lane == 0) { as_[wave] = s; as2_[wave] = s2; }
    __syncthreads();
    if (tid == 0) {
        u32 S = as_[0] + as_[1] + as_[2] + as_[3];
        u64 S2 = as2_[0] + as2_[1] + as2_[2] + as2_[3];
        double m2 = (double)S * 0.25 / (double)BATCH;
        double e2 = (double)S2 * 0.0625 / (double)BATCH;
        double v2 = e2 - m2 * m2;
        float rs = (float)(1.0 / sqrt(v2 + 1e-5));
        float c1 = rs * g2[j];
        float c0 = fmaf(-(float)m2, c1, b2[j]);
        bn2c[j] = c1 * 0.25f; bn2c[128 + j] = c0;
    }
}

__global__ __launch_bounds__(256) void k2_sstats(
        const u64* __restrict__ xbits, const u64* __restrict__ wbits,
        const float* __restrict__ bn2c,
        float* __restrict__ sS, float* __restrict__ sS2) {
    __shared__ u64 lb[128][4];
    int tid = threadIdx.x;
    ((ulonglong2*)&lb[0][0])[tid] =
        ((const ulonglong2*)(xbits + (size_t)blockIdx.x * 512))[tid];
    __syncthreads();
    int j = tid & 127, half = tid >> 7;
    if (j >= DIM) return;
    u64 q0 = wbits[j*4+0], q1 = wbits[j*4+1], y0 = wbits[j*4+2], y1 = wbits[j*4+3];
    bool hasY = (y0 | y1) != 0;
    float c1q = bn2c[j], c0 = bn2c[128 + j];
    float SsA = 0.f, Ss2A = 0.f, SsB = 0.f, Ss2B = 0.f;
    int r0 = half * 64;
    for (int r = r0; r < r0 + 64; r += 2) {
        u64 z0 = lb[r][2], z1 = lb[r][3];
        u32 hqa = hq_from_bits(lb[r][0], lb[r][1], z0, z1,
                               q0, q1, y0, y1, hasY, (z0 | z1) != 0);
        u64 w0 = lb[r+1][2], w1 = lb[r+1][3];
        u32 hqb = hq_from_bits(lb[r+1][0], lb[r+1][1], w0, w1,
                               q0, q1, y0, y1, hasY, (w0 | w1) != 0);
        float za = fmaf((float)hqa, c1q, c0);
        float sa = za * __builtin_amdgcn_rcpf(1.f + fabsf(za));
        SsA += sa; Ss2A = fmaf(sa, sa, Ss2A);
        float zb = fmaf((float)hqb, c1q, c0);
        float sb = zb * __builtin_amdgcn_rcpf(1.f + fabsf(zb));
        SsB += sb; Ss2B = fmaf(sb, sb, Ss2B);
    }
    int pidx = j * NPART + blockIdx.x * 2 + half;
    sS[pidx] = SsA + SsB; sS2[pidx] = Ss2A + Ss2B;
}

__global__ __launch_bounds__(256) void r2_sreduce(
        const float* __restrict__ sS, const float* __restrict__ sS2,
        const float* __restrict__ g1, const float* __restrict__ b1,
        const float* __restrict__ bn2c, const u32* __restrict__ lwq,
        u32* __restrict__ meta) {
    int j = blockIdx.x, tid = threadIdx.x;
    double s = 0.0, s2 = 0.0;
    for (int k = tid; k < NPART; k += 256) { s += (double)sS[j*NPART+k]; s2 += (double)sS2[j*NPART+k]; }
    for (int off = 32; off; off >>= 1) { s += __shfl_down(s, off, 64); s2 += __shfl_down(s2, off, 64); }
    __shared__ double ds_[4], ds2_[4];
    __shared__ float sd1, sd0;
    __shared__ u32 cnt[3];
    __shared__ u32 sfirst, slast;
    int lane = tid & 63, wave = tid >> 6;
    if (lane == 0) { ds_[wave] = s; ds2_[wave] = s2; }
    if (tid < 3) cnt[tid] = 0;
    __syncthreads();
    if (tid == 0) {
        double S = ds_[0] + ds_[1] + ds_[2] + ds_[3];
        double S2 = ds2_[0] + ds2_[1] + ds2_[2] + ds2_[3];
        double m1 = S / (double)BATCH;
        double v1 = S2 / (double)BATCH - m1 * m1;
        float rs = (float)(1.0 / sqrt(v1 + 1e-5));
        float d1 = rs * g1[j];
        float d0 = fmaf(-(float)m1, d1, b1[j]);
        sd1 = d1; sd0 = d0;
    }
    __syncthreads();
    float c1q = bn2c[j], c0 = bn2c[128 + j];
    float d1 = sd1, d0 = sd0;
    for (int hq = tid; hq < 481; hq += 256) {
        float z = fmaf((float)hq, c1q, c0);
        float sv = z * __builtin_amdgcn_rcpf(1.f + fabsf(z));
        float h1 = fmaf(sv, d1, d0);
        u32 hb2 = h1 > 0.f ? 2u : (h1 == 0.f ? 1u : 0u);
        atomicAdd(&cnt[hb2], 1u);
        if (hq == 0)   sfirst = hb2;
        if (hq == 480) slast  = hb2;
    }
    __syncthreads();
    if (tid == 0) {
        u32 n0 = cnt[0], n1 = cnt[1], n2 = cnt[2];
        u32 dec = (slast < sfirst) ? 1u : 0u;
        u32 A = dec ? n2 : n0;
        u32 B = A + n1;
        meta[2*j]   = A | (B << 9) | (dec << 18);
        meta[2*j+1] = lwq[j];
    }
}

__global__ __launch_bounds__(256) void k3_out(
        const u64* __restrict__ xbits, const u64* __restrict__ wbits,
        const u32* __restrict__ meta, const u32* __restrict__ oacc,
        u32* __restrict__ oqbuf, u32* __restrict__ oP) {
    __shared__ u64 sq0[DIM], sq1[DIM], smw[DIM], sy0[DIM], sy1[DIM];
    int tid = threadIdx.x;
    for (int k = tid; k < DIM; k += 256) {
        sq0[k] = wbits[k*4+0]; sq1[k] = wbits[k*4+1];
        sy0[k] = wbits[k*4+2]; sy1[k] = wbits[k*4+3];
        smw[k] = (u64)meta[2*k] | ((u64)meta[2*k+1] << 32);
    }
    __syncthreads();
    size_t row = (size_t)blockIdx.x * 256 + tid;
    const ulonglong2* xb = (const ulonglong2*)xbits;
    ulonglong2 rp = xb[row*2], rz = xb[row*2+1];
    u64 p0 = rp.x, p1 = rp.y, z0 = rz.x, z1 = rz.y;
    u32 oq = 0;
    for (int c = 0; c < DIM; c += CH) {
        ulonglong2 A[CH/2], B[CH/2], Mw[CH/2];
        #pragma unroll
        for (int t = 0; t < CH/2; ++t) {
            A[t] = *(const ulonglong2*)&sq0[c + 2*t];
            B[t] = *(const ulonglong2*)&sq1[c + 2*t];
            Mw[t] = *(const ulonglong2*)&smw[c + 2*t];
        }
        #pragma unroll
        for (int t = 0; t < CH/2; ++t) {
            proc_col(p0, p1, A[t].x, B[t].x, Mw[t].x, oq);
            proc_col(p0, p1, A[t].y, B[t].y, Mw[t].y, oq);
        }
    }
    bool slow = (oacc[8] != 0) | ((z0 | z1) != 0);
    if (__any(slow)) {
        if (slow) {
            oq = 0;
            for (int j = 0; j < DIM; ++j) {
                u64 y0 = sy0[j], y1 = sy1[j];
                u32 hq = hq_from_bits(p0, p1, z0, z1, sq0[j], sq1[j], y0, y1,
                                      (y0 | y1) != 0, (z0 | z1) != 0);
                u64 mw = smw[j];
                u32 m = (u32)mw, lw = (u32)(mw >> 32);
                u32 ge = (u32)(hq >= (m & 511u)) + (u32)(hq >= ((m >> 9) & 511u));
                oq += ((m & (1u << 18)) ? 2u - ge : ge) * lw;
            }
        }
    }
    oqbuf[row] = oq;
    u32 o0 = oq & 0xffffu, o1 = oq >> 16;
    u32 a = o0, b = o1, c2 = o0 * o0, d2 = o1 * o1;
    for (int off = 32; off; off >>= 1) {
        a += __shfl_down(a, off, 64);  b += __shfl_down(b, off, 64);
        c2 += __shfl_down(c2, off, 64); d2 += __shfl_down(d2, off, 64);
    }
    __shared__ u32 r0_[4], r1_[4], r2_[4], r3_[4];
    int lane = tid & 63, wv = tid >> 6;
    if (lane == 0) { r0_[wv] = a; r1_[wv] = b; r2_[wv] = c2; r3_[wv] = d2; }
    __syncthreads();
    if (tid == 0) {
        u32* dst = oP + (size_t)blockIdx.x * 4;
        dst[0] = r0_[0] + r0_[1] + r0_[2] + r0_[3];
        dst[1] = r1_[0] + r1_[1] + r1_[2] + r1_[3];
        dst[2] = r2_[0] + r2_[1] + r2_[2] + r2_[3];
        dst[3] = r3_[0] + r3_[1] + r3_[2] + r3_[3];
    }
}

__global__ __launch_bounds__(256) void k4_final(
        const u32* __restrict__ oqbuf, const u32* __restrict__ oP,
        float* __restrict__ out) {
    int tid = threadIdx.x;
    u64 a = 0, b = 0, c2 = 0, d2 = 0;
    for (int k = tid; k < NBLK3; k += 256) {
        uint4 p = ((const uint4*)oP)[k];
        a += p.x; b += p.y; c2 += p.z; d2 += p.w;
    }
    for (int off = 32; off; off >>= 1) {
        a += __shfl_down(a, off, 64);  b += __shfl_down(b, off, 64);
        c2 += __shfl_down(c2, off, 64); d2 += __shfl_down(d2, off, 64);
    }
    __shared__ u64 s0_[4], s1_[4], s2_[4], s3_[4];
    __shared__ float sfin[4];
    int lane = tid & 63, wv = tid >> 6;
    if (lane == 0) { s0_[wv] = a; s1_[wv] = b; s2_[wv] = c2; s3_[wv] = d2; }
    __syncthreads();
    if (tid < 2) {
        u64 S  = (tid == 0) ? s0_[0]+s0_[1]+s0_[2]+s0_[3] : s1_[0]+s1_[1]+s1_[2]+s1_[3];
        u64 S2 = (tid == 0) ? s2_[0]+s2_[1]+s2_[2]+s2_[3] : s3_[0]+s3_[1]+s3_[2]+s3_[3];
        double av = (double)S * 0.25 / (double)BATCH;
        double e2 = (double)S2 * 0.0625 / (double)BATCH;
        double vo = e2 - av * av;
        sfin[tid]     = (float)av;
        sfin[2 + tid] = (float)(1.0 / sqrt(vo + 1e-5));
    }
    __syncthreads();
    size_t row = (size_t)blockIdx.x * 256 + tid;
    u32 v = oqbuf[row];
    float o0 = ((float)(v & 0xffffu) * 0.25f - sfin[0]) * sfin[2];
    float o1 = ((float)(v >> 16)     * 0.25f - sfin[1]) * sfin[3];
    float m = fmaxf(o0, o1);
    float l0 = o0 - m, l1 = o1 - m;
    float ls = logf(expf(l0) + expf(l1));
    ((float2*)out)[row] = make_float2(l0 - ls, l1 - ls);
}

extern "C" void kernel_launch(void* const* d_in, const int* in_sizes, int n_in,
                              void* d_out, int out_size, void* d_ws, size_t ws_size,
                              hipStream_t stream) {
    const float* x  = (const float*)d_in[0];
    const float* cw = (const float*)d_in[1];
    const float* g2 = (const float*)d_in[2];
    const float* b2 = (const float*)d_in[3];
    const float* g1 = (const float*)d_in[4];
    const float* b1 = (const float*)d_in[5];
    const float* lw = (const float*)d_in[6];
    // d_in[7] (lin_b) cancels through the final no-affine batchnorm
    float* out = (float*)d_out;
    if (ws_size < (size_t)WS_TOTAL) return;

    char* ws = (char*)d_ws;
    u64* xbits = (u64*)(ws + WS_XBITS);
    u64* wbits = (u64*)(ws + WS_WBITS);
    u32* lwq   = (u32*)(ws + WS_LWQ);
    u32* meta  = (u32*)(ws + WS_META);
    u32* hP    = (u32*)(ws + WS_HS);
    u32* h2P   = (u32*)(ws + WS_HS2);
    float* sP  = (float*)(ws + WS_SS);
    float* s2P = (float*)(ws + WS_SS2);
    float* bn2c = (float*)(ws + WS_BN2C);
    u32* oqbuf = (u32*)(ws + WS_OQ);
    u32* oacc  = (u32*)(ws + WS_OACC);
    u32* oP    = (u32*)(ws + WS_OP);

    void* kargs[] = { (void*)&x, (void*)&cw, (void*)&g2, (void*)&b2,
                      (void*)&g1, (void*)&b1, (void*)&lw, (void*)&out,
                      (void*)&hP, (void*)&h2P, (void*)&sP, (void*)&s2P,
                      (void*)&bn2c, (void*)&meta, (void*)&oP };
    hipError_t err = hipLaunchCooperativeKernel(
        reinterpret_cast<void*>(mega), dim3(NBLKM), dim3(256), kargs, 0, stream);
    if (err != hipSuccess) {
        // Fallback: proven round-8 multi-kernel path (bit-identical output)
        kw_pack       <<<1, 256, 0, stream>>>(cw, lw, wbits, lwq, oacc);
        k1_pack_hstats<<<NBLK1, 256, 0, stream>>>(x, wbits, xbits, hP, h2P);
        r1_hreduce    <<<DIM, 256, 0, stream>>>(hP, h2P, g2, b2, bn2c);
        k2_sstats     <<<NBLK1, 256, 0, stream>>>(xbits, wbits, bn2c, sP, s2P);
        r2_sreduce    <<<DIM, 256, 0, stream>>>(sP, s2P, g1, b1, bn2c, lwq, meta);
        k3_out        <<<NBLK3, 256, 0, stream>>>(xbits, wbits, meta, oacc, oqbuf, oP);
        k4_final      <<<NBLK3, 256, 0, stream>>>(oqbuf, oP, out);
    }
}

// Round 10
// 112.454 us; speedup vs baseline: 5.6572x; 5.6572x over previous
//
#include <hip/hip_runtime.h>
#include <stdint.h>
#include <math.h>

typedef unsigned long long u64;
typedef uint32_t u32;

#define BATCH   262144
#define DIM     120
#define NBLKA   1024      // k1: 256 rows per block
#define NBLK1   2048      // k2: 128 rows per block
#define NPART   4096      // k2 partial slots per column
#define CH      8         // k3: columns per register chunk
#define NBLK3   1024      // k3 blocks (256 rows each)

// Bit permutation (x and w MUST match): element c -> plane (c&3), bit (c>>2).
// p0 = plane0 | plane1<<30 ; p1 = plane2 | plane3<<30 (60 bits used).

// ---------------- workspace layout (bytes) ----------------
#define WS_XBITS   0              // u64[BATCH*4]            8,388,608
#define WS_WBITS   8388608        // u64[128*4]
#define WS_META    8393216        // u32[256]
#define WS_HS      8394240        // u32[120*2048]
#define WS_HS2     10360320      // u32[120*2048]
#define WS_SS      12326400      // f32[120*4096]
#define WS_SS2     14292480      // f32[120*4096]
#define WS_BN2C    16258560      // f32[256]
#define WS_OQ      16259584      // u32[BATCH]
#define WS_OACC    17308160      // u32 yflag @ word 8
#define WS_OP      17308224      // u32[1024*4]
#define WS_TOTAL   17324624

__device__ __forceinline__ u32 hq_from_bits(u64 p0, u64 p1, u64 z0, u64 z1,
                                            u64 q0, u64 q1, u64 y0, u64 y1,
                                            bool hasY, bool hasZ) {
    u32 hq = (u32)(__popcll(p0 & q0) + __popcll(p1 & q1)) << 2;
    if (hasY)
        hq += 2u * (u32)(__popcll(p0 & y0) + __popcll(p1 & y1))
            + (u32)(__popcll(z0 & y0) + __popcll(z1 & y1));
    if (hasZ)
        hq += 2u * (u32)(__popcll(z0 & q0) + __popcll(z1 & q1));
    return hq;   // == 4 * h, exact integer in [0, 480]
}

__device__ __forceinline__ void proc_col(u64 p0, u64 p1, u64 q0, u64 q1,
                                         u64 mw, u32& oq) {
    u32 hq = ((u32)(__popcll(p0 & q0) + __popcll(p1 & q1))) << 2;
    u32 m  = (u32)mw;
    u32 lw = (u32)(mw >> 32);
    u32 ge = (u32)(hq >= (m & 511u)) + (u32)(hq >= ((m >> 9) & 511u));
    u32 hb2 = (m & (1u << 18)) ? 2u - ge : ge;
    oq += hb2 * lw;
}

// K1 (kw_pack fused): every block packs conv_w into LDS redundantly
// (57.6 KB L2-resident, overlaps x loads); block 0 publishes wbits + yflag.
// Then packs its 256 x-rows, stores xbits, computes integer h-stats.
__global__ __launch_bounds__(256) void k1_pack_hstats(
        const float* __restrict__ x, const float* __restrict__ w,
        u64* __restrict__ wbits, u32* __restrict__ oacc,
        u64* __restrict__ xbits, u32* __restrict__ hP, u32* __restrict__ h2P) {
    __shared__ __align__(16) u64 lb[256][4];
    __shared__ __align__(16) u64 sw[128][4];
    __shared__ u32 swf[4];
    int tid = threadIdx.x, lane = tid & 63, wv = tid >> 6;
    int l = lane & 31, h = lane >> 5;
    int bid = blockIdx.x;
    const u64 M = 0x3FFFFFFFull;

    // ---- conv_w pack (whole 120x120 per block) ----
    u64 accy = 0;
    for (int jj = wv * 2; jj < DIM; jj += 8) {
        int j = jj + h;
        float4 v = make_float4(-1.f, -1.f, -1.f, -1.f);
        if (l < 30) v = *(const float4*)(w + (size_t)j * DIM + l * 4);
        u64 m0 = __ballot(v.x > 0.f), m1 = __ballot(v.y > 0.f);
        u64 m2 = __ballot(v.z > 0.f), m3 = __ballot(v.w > 0.f);
        u64 n0 = __ballot(v.x == 0.f), n1 = __ballot(v.y == 0.f);
        u64 n2 = __ballot(v.z == 0.f), n3 = __ballot(v.w == 0.f);
        accy |= (n0 | n1 | n2 | n3);
        if (l == 0) {
            u32 sh = h ? 32 : 0;
            sw[j][0] = ((m0>>sh)&M) | (((m1>>sh)&M) << 30);
            sw[j][1] = ((m2>>sh)&M) | (((m3>>sh)&M) << 30);
            sw[j][2] = ((n0>>sh)&M) | (((n1>>sh)&M) << 30);
            sw[j][3] = ((n2>>sh)&M) | (((n3>>sh)&M) << 30);
        }
    }
    if (tid >= 120 && tid < 128) { sw[tid][0]=0; sw[tid][1]=0; sw[tid][2]=0; sw[tid][3]=0; }
    { u32 af = __any(accy != 0) ? 1u : 0u; if (lane == 0) swf[wv] = af; }

    // ---- x pack: 256 rows, 2 rows per wave-iteration ----
    for (int rr = 0; rr < 32; ++rr) {
        int r = rr * 8 + wv * 2 + h;
        float4 v = make_float4(-1.f, -1.f, -1.f, -1.f);
        if (l < 30) v = *(const float4*)(x + ((size_t)bid * 256 + r) * DIM + l * 4);
        u64 m0 = __ballot(v.x > 0.f), m1 = __ballot(v.y > 0.f);
        u64 m2 = __ballot(v.z > 0.f), m3 = __ballot(v.w > 0.f);
        u64 n0 = __ballot(v.x == 0.f), n1 = __ballot(v.y == 0.f);
        u64 n2 = __ballot(v.z == 0.f), n3 = __ballot(v.w == 0.f);
        if (l == 0) {
            u32 sh = h ? 32 : 0;
            lb[r][0] = ((m0>>sh)&M) | (((m1>>sh)&M) << 30);
            lb[r][1] = ((m2>>sh)&M) | (((m3>>sh)&M) << 30);
            lb[r][2] = ((n0>>sh)&M) | (((n1>>sh)&M) << 30);
            lb[r][3] = ((n2>>sh)&M) | (((n3>>sh)&M) << 30);
        }
    }
    __syncthreads();

    // ---- publish wbits/yflag (block 0) + store xbits ----
    if (bid == 0) {
        ((u64*)wbits)[tid]       = ((const u64*)sw)[tid];
        ((u64*)wbits)[tid + 256] = ((const u64*)sw)[tid + 256];
        if (tid == 0) oacc[8] = (swf[0] | swf[1] | swf[2] | swf[3]) ? 1u : 0u;
    }
    {
        ulonglong2* dst = (ulonglong2*)(xbits + (size_t)bid * 1024);
        const ulonglong2* src = (const ulonglong2*)&lb[0][0];
        dst[tid] = src[tid];
        dst[tid + 256] = src[tid + 256];
    }

    // ---- integer h-stats: thread <-> (column, half of 256 rows) ----
    int j = tid & 127, hh = tid >> 7;
    if (j < DIM) {
        u64 q0 = sw[j][0], q1 = sw[j][1], y0 = sw[j][2], y1 = sw[j][3];
        bool hasY = (y0 | y1) != 0;
        u32 S = 0, S2 = 0;
        int r0 = hh * 128;
        for (int r = r0; r < r0 + 128; ++r) {
            u64 z0 = lb[r][2], z1 = lb[r][3];
            u32 hq = hq_from_bits(lb[r][0], lb[r][1], z0, z1,
                                  q0, q1, y0, y1, hasY, (z0 | z1) != 0);
            S += hq; S2 += hq * hq;
        }
        hP[j*2048 + bid*2 + hh] = S;
        h2P[j*2048 + bid*2 + hh] = S2;
    }
}

// R1: reduce integer h-stats -> fold BN2 into  z = fma(hq, c1q, c0)
__global__ __launch_bounds__(256) void r1_hreduce(
        const u32* __restrict__ hP, const u32* __restrict__ h2P,
        const float* __restrict__ g2, const float* __restrict__ b2,
        float* __restrict__ bn2c) {
    int j = blockIdx.x, tid = threadIdx.x;
    u32 s = 0; u64 s2 = 0;
    for (int k = tid; k < 2048; k += 256) { s += hP[j*2048+k]; s2 += (u64)h2P[j*2048+k]; }
    for (int off = 32; off; off >>= 1) { s += __shfl_down(s, off, 64); s2 += __shfl_down(s2, off, 64); }
    __shared__ u32 as_[4]; __shared__ u64 as2_[4];
    int lane = tid & 63, wave = tid >> 6;
    if (lane == 0) { as_[wave] = s; as2_[wave] = s2; }
    __syncthreads();
    if (tid == 0) {
        u32 S = as_[0] + as_[1] + as_[2] + as_[3];
        u64 S2 = as2_[0] + as2_[1] + as2_[2] + as2_[3];
        double m2 = (double)S * 0.25 / (double)BATCH;
        double e2 = (double)S2 * 0.0625 / (double)BATCH;
        double v2 = e2 - m2 * m2;
        float rs = (float)(1.0 / sqrt(v2 + 1e-5));
        float c1 = rs * g2[j];
        float c0 = fmaf(-(float)m2, c1, b2[j]);
        bn2c[j] = c1 * 0.25f; bn2c[128 + j] = c0;
    }
}

// K2: stage bits in LDS, recompute hq, softsign stats (dual f32 accumulators)
__global__ __launch_bounds__(256) void k2_sstats(
        const u64* __restrict__ xbits, const u64* __restrict__ wbits,
        const float* __restrict__ bn2c,
        float* __restrict__ sS, float* __restrict__ sS2) {
    __shared__ u64 lb[128][4];
    int tid = threadIdx.x;
    ((ulonglong2*)&lb[0][0])[tid] =
        ((const ulonglong2*)(xbits + (size_t)blockIdx.x * 512))[tid];
    __syncthreads();
    int j = tid & 127, half = tid >> 7;
    if (j >= DIM) return;
    u64 q0 = wbits[j*4+0], q1 = wbits[j*4+1], y0 = wbits[j*4+2], y1 = wbits[j*4+3];
    bool hasY = (y0 | y1) != 0;
    float c1q = bn2c[j], c0 = bn2c[128 + j];
    float SsA = 0.f, Ss2A = 0.f, SsB = 0.f, Ss2B = 0.f;
    int r0 = half * 64;
    for (int r = r0; r < r0 + 64; r += 2) {
        u64 z0 = lb[r][2], z1 = lb[r][3];
        u32 hqa = hq_from_bits(lb[r][0], lb[r][1], z0, z1,
                               q0, q1, y0, y1, hasY, (z0 | z1) != 0);
        u64 w0 = lb[r+1][2], w1 = lb[r+1][3];
        u32 hqb = hq_from_bits(lb[r+1][0], lb[r+1][1], w0, w1,
                               q0, q1, y0, y1, hasY, (w0 | w1) != 0);
        float za = fmaf((float)hqa, c1q, c0);
        float sa = za * __builtin_amdgcn_rcpf(1.f + fabsf(za));
        SsA += sa; Ss2A = fmaf(sa, sa, Ss2A);
        float zb = fmaf((float)hqb, c1q, c0);
        float sb = zb * __builtin_amdgcn_rcpf(1.f + fabsf(zb));
        SsB += sb; Ss2B = fmaf(sb, sb, Ss2B);
    }
    int pidx = j * NPART + blockIdx.x * 2 + half;
    sS[pidx] = SsA + SsB; sS2[pidx] = Ss2A + Ss2B;
}

// R2: reduce softsign stats (f64), fold BN1, derive the two integer
// thresholds per column; lin_w binarize computed inline (2 floats).
__global__ __launch_bounds__(256) void r2_sreduce(
        const float* __restrict__ sS, const float* __restrict__ sS2,
        const float* __restrict__ g1, const float* __restrict__ b1,
        const float* __restrict__ bn2c, const float* __restrict__ lw,
        u32* __restrict__ meta) {
    int j = blockIdx.x, tid = threadIdx.x;
    double s = 0.0, s2 = 0.0;
    for (int k = tid; k < NPART; k += 256) { s += (double)sS[j*NPART+k]; s2 += (double)sS2[j*NPART+k]; }
    for (int off = 32; off; off >>= 1) { s += __shfl_down(s, off, 64); s2 += __shfl_down(s2, off, 64); }
    __shared__ double ds_[4], ds2_[4];
    __shared__ float sd1, sd0;
    __shared__ u32 cnt[3];
    __shared__ u32 sfirst, slast;
    int lane = tid & 63, wave = tid >> 6;
    if (lane == 0) { ds_[wave] = s; ds2_[wave] = s2; }
    if (tid < 3) cnt[tid] = 0;
    __syncthreads();
    if (tid == 0) {
        double S = ds_[0] + ds_[1] + ds_[2] + ds_[3];
        double S2 = ds2_[0] + ds2_[1] + ds2_[2] + ds2_[3];
        double m1 = S / (double)BATCH;
        double v1 = S2 / (double)BATCH - m1 * m1;
        float rs = (float)(1.0 / sqrt(v1 + 1e-5));
        float d1 = rs * g1[j];
        float d0 = fmaf(-(float)m1, d1, b1[j]);
        sd1 = d1; sd0 = d0;
    }
    __syncthreads();
    float c1q = bn2c[j], c0 = bn2c[128 + j];
    float d1 = sd1, d0 = sd0;
    for (int hq = tid; hq < 481; hq += 256) {
        float z = fmaf((float)hq, c1q, c0);
        float sv = z * __builtin_amdgcn_rcpf(1.f + fabsf(z));
        float h1 = fmaf(sv, d1, d0);
        u32 hb2 = h1 > 0.f ? 2u : (h1 == 0.f ? 1u : 0u);
        atomicAdd(&cnt[hb2], 1u);
        if (hq == 0)   sfirst = hb2;
        if (hq == 480) slast  = hb2;
    }
    __syncthreads();
    if (tid == 0) {
        u32 n0 = cnt[0], n1 = cnt[1], n2 = cnt[2];
        u32 dec = (slast < sfirst) ? 1u : 0u;
        u32 A = dec ? n2 : n0;
        u32 B = A + n1;
        float w0 = lw[j], w1 = lw[DIM + j];
        u32 l0 = w0 > 0.f ? 2u : (w0 == 0.f ? 1u : 0u);
        u32 l1 = w1 > 0.f ? 2u : (w1 == 0.f ? 1u : 0u);
        meta[2*j]   = A | (B << 9) | (dec << 18);
        meta[2*j+1] = l0 | (l1 << 16);
    }
}

// K3: thread <-> row, chunked-register column loop, per-block stat partials
// to distinct addresses (no global atomics).
__global__ __launch_bounds__(256) void k3_out(
        const u64* __restrict__ xbits, const u64* __restrict__ wbits,
        const u32* __restrict__ meta, const u32* __restrict__ oacc,
        u32* __restrict__ oqbuf, u32* __restrict__ oP) {
    __shared__ u64 sq0[DIM], sq1[DIM], smw[DIM], sy0[DIM], sy1[DIM];
    int tid = threadIdx.x;
    for (int k = tid; k < DIM; k += 256) {
        sq0[k] = wbits[k*4+0]; sq1[k] = wbits[k*4+1];
        sy0[k] = wbits[k*4+2]; sy1[k] = wbits[k*4+3];
        smw[k] = (u64)meta[2*k] | ((u64)meta[2*k+1] << 32);
    }
    __syncthreads();
    size_t row = (size_t)blockIdx.x * 256 + tid;
    const ulonglong2* xb = (const ulonglong2*)xbits;
    ulonglong2 rp = xb[row*2], rz = xb[row*2+1];
    u64 p0 = rp.x, p1 = rp.y, z0 = rz.x, z1 = rz.y;
    u32 oq = 0;
    for (int c = 0; c < DIM; c += CH) {
        ulonglong2 A[CH/2], B[CH/2], Mw[CH/2];
        #pragma unroll
        for (int t = 0; t < CH/2; ++t) {
            A[t] = *(const ulonglong2*)&sq0[c + 2*t];
            B[t] = *(const ulonglong2*)&sq1[c + 2*t];
            Mw[t] = *(const ulonglong2*)&smw[c + 2*t];
        }
        #pragma unroll
        for (int t = 0; t < CH/2; ++t) {
            proc_col(p0, p1, A[t].x, B[t].x, Mw[t].x, oq);
            proc_col(p0, p1, A[t].y, B[t].y, Mw[t].y, oq);
        }
    }
    bool slow = (oacc[8] != 0) | ((z0 | z1) != 0);
    if (__any(slow)) {
        if (slow) {          // exact full recompute (expected ~2 rows/batch)
            oq = 0;
            for (int j = 0; j < DIM; ++j) {
                u64 y0 = sy0[j], y1 = sy1[j];
                u32 hq = hq_from_bits(p0, p1, z0, z1, sq0[j], sq1[j], y0, y1,
                                      (y0 | y1) != 0, (z0 | z1) != 0);
                u64 mw = smw[j];
                u32 m = (u32)mw, lw = (u32)(mw >> 32);
                u32 ge = (u32)(hq >= (m & 511u)) + (u32)(hq >= ((m >> 9) & 511u));
                oq += ((m & (1u << 18)) ? 2u - ge : ge) * lw;
            }
        }
    }
    oqbuf[row] = oq;
    u32 o0 = oq & 0xffffu, o1 = oq >> 16;
    u32 a = o0, b = o1, c2 = o0 * o0, d2 = o1 * o1;
    for (int off = 32; off; off >>= 1) {
        a += __shfl_down(a, off, 64);  b += __shfl_down(b, off, 64);
        c2 += __shfl_down(c2, off, 64); d2 += __shfl_down(d2, off, 64);
    }
    __shared__ u32 r0_[4], r1_[4], r2_[4], r3_[4];
    int lane = tid & 63, wv = tid >> 6;
    if (lane == 0) { r0_[wv] = a; r1_[wv] = b; r2_[wv] = c2; r3_[wv] = d2; }
    __syncthreads();
    if (tid == 0) {
        u32* dst = oP + (size_t)blockIdx.x * 4;
        dst[0] = r0_[0] + r0_[1] + r0_[2] + r0_[3];
        dst[1] = r1_[0] + r1_[1] + r1_[2] + r1_[3];
        dst[2] = r2_[0] + r2_[1] + r2_[2] + r2_[3];
        dst[3] = r3_[0] + r3_[1] + r3_[2] + r3_[3];
    }
}

// K4: each block redundantly reduces the 16KB oP partials (exact integers,
// f64 finalize), then normalizes its 256 rows + 2-class log_softmax.
__global__ __launch_bounds__(256) void k4_final(
        const u32* __restrict__ oqbuf, const u32* __restrict__ oP,
        float* __restrict__ out) {
    int tid = threadIdx.x;
    u64 a = 0, b = 0, c2 = 0, d2 = 0;
    for (int k = tid; k < NBLK3; k += 256) {
        uint4 p = ((const uint4*)oP)[k];
        a += p.x; b += p.y; c2 += p.z; d2 += p.w;
    }
    for (int off = 32; off; off >>= 1) {
        a += __shfl_down(a, off, 64);  b += __shfl_down(b, off, 64);
        c2 += __shfl_down(c2, off, 64); d2 += __shfl_down(d2, off, 64);
    }
    __shared__ u64 s0_[4], s1_[4], s2_[4], s3_[4];
    __shared__ float sfin[4];
    int lane = tid & 63, wv = tid >> 6;
    if (lane == 0) { s0_[wv] = a; s1_[wv] = b; s2_[wv] = c2; s3_[wv] = d2; }
    __syncthreads();
    if (tid < 2) {
        u64 S  = (tid == 0) ? s0_[0]+s0_[1]+s0_[2]+s0_[3] : s1_[0]+s1_[1]+s1_[2]+s1_[3];
        u64 S2 = (tid == 0) ? s2_[0]+s2_[1]+s2_[2]+s2_[3] : s3_[0]+s3_[1]+s3_[2]+s3_[3];
        double av = (double)S * 0.25 / (double)BATCH;
        double e2 = (double)S2 * 0.0625 / (double)BATCH;
        double vo = e2 - av * av;
        sfin[tid]     = (float)av;
        sfin[2 + tid] = (float)(1.0 / sqrt(vo + 1e-5));
    }
    __syncthreads();
    size_t row = (size_t)blockIdx.x * 256 + tid;
    u32 v = oqbuf[row];
    float o0 = ((float)(v & 0xffffu) * 0.25f - sfin[0]) * sfin[2];
    float o1 = ((float)(v >> 16)     * 0.25f - sfin[1]) * sfin[3];
    float m = fmaxf(o0, o1);
    float l0 = o0 - m, l1 = o1 - m;
    float ls = logf(expf(l0) + expf(l1));
    ((float2*)out)[row] = make_float2(l0 - ls, l1 - ls);
}

extern "C" void kernel_launch(void* const* d_in, const int* in_sizes, int n_in,
                              void* d_out, int out_size, void* d_ws, size_t ws_size,
                              hipStream_t stream) {
    const float* x  = (const float*)d_in[0];
    const float* cw = (const float*)d_in[1];
    const float* g2 = (const float*)d_in[2];
    const float* b2 = (const float*)d_in[3];
    const float* g1 = (const float*)d_in[4];
    const float* b1 = (const float*)d_in[5];
    const float* lw = (const float*)d_in[6];
    // d_in[7] (lin_b) cancels through the final no-affine batchnorm
    float* out = (float*)d_out;
    if (ws_size < (size_t)WS_TOTAL) return;   // fail loudly via poisoned d_out

    char* ws = (char*)d_ws;
    u64* xbits = (u64*)(ws + WS_XBITS);
    u64* wbits = (u64*)(ws + WS_WBITS);
    u32* meta  = (u32*)(ws + WS_META);
    u32* hP    = (u32*)(ws + WS_HS);
    u32* h2P   = (u32*)(ws + WS_HS2);
    float* sP  = (float*)(ws + WS_SS);
    float* s2P = (float*)(ws + WS_SS2);
    float* bn2c = (float*)(ws + WS_BN2C);
    u32* oqbuf = (u32*)(ws + WS_OQ);
    u32* oacc  = (u32*)(ws + WS_OACC);
    u32* oP    = (u32*)(ws + WS_OP);

    k1_pack_hstats<<<NBLKA, 256, 0, stream>>>(x, cw, wbits, oacc, xbits, hP, h2P);
    r1_hreduce    <<<DIM, 256, 0, stream>>>(hP, h2P, g2, b2, bn2c);
    k2_sstats     <<<NBLK1, 256, 0, stream>>>(xbits, wbits, bn2c, sP, s2P);
    r2_sreduce    <<<DIM, 256, 0, stream>>>(sP, s2P, g1, b1, bn2c, lw, meta);
    k3_out        <<<NBLK3, 256, 0, stream>>>(xbits, wbits, meta, oacc, oqbuf, oP);
    k4_final      <<<NBLK3, 256, 0, stream>>>(oqbuf, oP, out);
}

// Round 11
// 110.377 us; speedup vs baseline: 5.7637x; 1.0188x over previous
//
#include <hip/hip_runtime.h>
#include <stdint.h>
#include <math.h>

typedef unsigned long long u64;
typedef uint32_t u32;

#define BATCH   262144
#define DIM     120
#define NBLK1   2048      // k1/k2: 128 rows per block
#define NPART   4096      // partial slots per column (2 halves * 2048 blocks)
#define CH      8         // k3: columns per register chunk
#define NBLK3   1024      // k3 blocks (256 rows each)

// Bit permutation (x and w MUST match): element c -> plane (c&3), bit (c>>2).
// p0 = plane0 | plane1<<30 ; p1 = plane2 | plane3<<30 (60 bits used).

// ---------------- workspace layout (bytes) ----------------
#define WS_XBITS   0              // u64[BATCH*4]            8,388,608
#define WS_WBITS   8388608        // u64[128*4]
#define WS_META    8393216        // u32[256]
#define WS_HS      8394240        // u32[120*4096]
#define WS_HS2     10360320      // u32[120*4096]
#define WS_SS      12326400      // f32[120*4096]
#define WS_SS2     14292480      // f32[120*4096]
#define WS_BN2C    16258560      // f32[256]
#define WS_OQ      16259584      // u32[BATCH]
#define WS_OACC    17308160      // u32 yflag @ word 8
#define WS_OP      17308224      // u32[1024*4]
#define WS_TOTAL   17324624

__device__ __forceinline__ u32 hq_from_bits(u64 p0, u64 p1, u64 z0, u64 z1,
                                            u64 q0, u64 q1, u64 y0, u64 y1,
                                            bool hasY, bool hasZ) {
    u32 hq = (u32)(__popcll(p0 & q0) + __popcll(p1 & q1)) << 2;
    if (hasY)
        hq += 2u * (u32)(__popcll(p0 & y0) + __popcll(p1 & y1))
            + (u32)(__popcll(z0 & y0) + __popcll(z1 & y1));
    if (hasZ)
        hq += 2u * (u32)(__popcll(z0 & q0) + __popcll(z1 & q1));
    return hq;   // == 4 * h, exact integer in [0, 480]
}

__device__ __forceinline__ void proc_col(u64 p0, u64 p1, u64 q0, u64 q1,
                                         u64 mw, u32& oq) {
    u32 hq = ((u32)(__popcll(p0 & q0) + __popcll(p1 & q1))) << 2;
    u32 m  = (u32)mw;
    u32 lw = (u32)(mw >> 32);
    u32 ge = (u32)(hq >= (m & 511u)) + (u32)(hq >= ((m >> 9) & 511u));
    u32 hb2 = (m & (1u << 18)) ? 2u - ge : ge;
    oq += hb2 * lw;
}

// K1 (kw_pack fused): 2048 blocks x 128 rows (8 blocks/CU for TLP).
// x-pack uses 4 batched independent float4 loads per iteration (ILP4);
// stats loop uses 2-row dual accumulators. Block 0 publishes wbits+yflag.
__global__ __launch_bounds__(256) void k1_pack_hstats(
        const float* __restrict__ x, const float* __restrict__ w,
        u64* __restrict__ wbits, u32* __restrict__ oacc,
        u64* __restrict__ xbits, u32* __restrict__ hP, u32* __restrict__ h2P) {
    __shared__ __align__(16) u64 lb[128][4];
    __shared__ __align__(16) u64 sw[128][4];
    __shared__ u32 swf[4];
    int tid = threadIdx.x, lane = tid & 63, wv = tid >> 6;
    int l = lane & 31, h = lane >> 5;
    int bid = blockIdx.x;
    const u64 M = 0x3FFFFFFFull;

#define PACKROW(dst, v, r) do { \
    u64 m0 = __ballot((v).x > 0.f), m1 = __ballot((v).y > 0.f); \
    u64 m2 = __ballot((v).z > 0.f), m3 = __ballot((v).w > 0.f); \
    u64 n0 = __ballot((v).x == 0.f), n1 = __ballot((v).y == 0.f); \
    u64 n2 = __ballot((v).z == 0.f), n3 = __ballot((v).w == 0.f); \
    if (l == 0) { u32 sh = h ? 32 : 0; \
        dst[r][0] = ((m0>>sh)&M) | (((m1>>sh)&M) << 30); \
        dst[r][1] = ((m2>>sh)&M) | (((m3>>sh)&M) << 30); \
        dst[r][2] = ((n0>>sh)&M) | (((n1>>sh)&M) << 30); \
        dst[r][3] = ((n2>>sh)&M) | (((n3>>sh)&M) << 30); } \
} while (0)

    // ---- conv_w pack (whole 120x120 per block; L2-resident) ----
    u64 accy = 0;
    for (int jj = wv * 2; jj < DIM; jj += 8) {
        int j = jj + h;
        float4 v = make_float4(-1.f, -1.f, -1.f, -1.f);
        if (l < 30) v = *(const float4*)(w + (size_t)j * DIM + l * 4);
        u64 n0 = __ballot(v.x == 0.f), n1 = __ballot(v.y == 0.f);
        u64 n2 = __ballot(v.z == 0.f), n3 = __ballot(v.w == 0.f);
        accy |= (n0 | n1 | n2 | n3);
        u64 m0 = __ballot(v.x > 0.f), m1 = __ballot(v.y > 0.f);
        u64 m2 = __ballot(v.z > 0.f), m3 = __ballot(v.w > 0.f);
        if (l == 0) {
            u32 sh = h ? 32 : 0;
            sw[j][0] = ((m0>>sh)&M) | (((m1>>sh)&M) << 30);
            sw[j][1] = ((m2>>sh)&M) | (((m3>>sh)&M) << 30);
            sw[j][2] = ((n0>>sh)&M) | (((n1>>sh)&M) << 30);
            sw[j][3] = ((n2>>sh)&M) | (((n3>>sh)&M) << 30);
        }
    }
    if (tid >= 120 && tid < 128) { sw[tid][0]=0; sw[tid][1]=0; sw[tid][2]=0; sw[tid][3]=0; }
    { u32 af = __any(accy != 0) ? 1u : 0u; if (lane == 0) swf[wv] = af; }

    // ---- x pack: 128 rows, ILP4 (4 independent loads, then ballots) ----
    {
        int rb = wv * 2 + h;               // 0..7
        const float4 zf = make_float4(-1.f, -1.f, -1.f, -1.f);
        for (int rr = 0; rr < 16; rr += 4) {
            float4 v0 = zf, v1 = zf, v2 = zf, v3 = zf;
            if (l < 30) {
                const float* p = x + ((size_t)bid * 128 + (size_t)rr * 8 + rb) * DIM + l * 4;
                v0 = *(const float4*)(p);
                v1 = *(const float4*)(p + 8 * DIM);
                v2 = *(const float4*)(p + 16 * DIM);
                v3 = *(const float4*)(p + 24 * DIM);
            }
            PACKROW(lb, v0, rr * 8 + rb);
            PACKROW(lb, v1, (rr + 1) * 8 + rb);
            PACKROW(lb, v2, (rr + 2) * 8 + rb);
            PACKROW(lb, v3, (rr + 3) * 8 + rb);
        }
    }
    __syncthreads();

    // ---- publish wbits/yflag (block 0) + store xbits ----
    if (bid == 0) {
        ((u64*)wbits)[tid]       = ((const u64*)sw)[tid];
        ((u64*)wbits)[tid + 256] = ((const u64*)sw)[tid + 256];
        if (tid == 0) oacc[8] = (swf[0] | swf[1] | swf[2] | swf[3]) ? 1u : 0u;
    }
    ((ulonglong2*)(xbits + (size_t)bid * 512))[tid] =
        ((const ulonglong2*)&lb[0][0])[tid];

    // ---- integer h-stats: thread <-> column, 2-row ILP accumulators ----
    int j = tid & 127, half = tid >> 7;
    if (j < DIM) {
        u64 q0 = sw[j][0], q1 = sw[j][1], y0 = sw[j][2], y1 = sw[j][3];
        bool hasY = (y0 | y1) != 0;
        u32 SA = 0, S2A = 0, SB = 0, S2B = 0;
        int r0 = half * 64;
        for (int r = r0; r < r0 + 64; r += 2) {
            ulonglong2 a0 = *(const ulonglong2*)&lb[r][0];
            ulonglong2 a1 = *(const ulonglong2*)&lb[r][2];
            ulonglong2 b0 = *(const ulonglong2*)&lb[r+1][0];
            ulonglong2 b1 = *(const ulonglong2*)&lb[r+1][2];
            u32 hqa = hq_from_bits(a0.x, a0.y, a1.x, a1.y,
                                   q0, q1, y0, y1, hasY, (a1.x | a1.y) != 0);
            u32 hqb = hq_from_bits(b0.x, b0.y, b1.x, b1.y,
                                   q0, q1, y0, y1, hasY, (b1.x | b1.y) != 0);
            SA += hqa; S2A += hqa * hqa;
            SB += hqb; S2B += hqb * hqb;
        }
        int pidx = j * NPART + bid * 2 + half;
        hP[pidx] = SA + SB; h2P[pidx] = S2A + S2B;
    }
#undef PACKROW
}

// R1: reduce integer h-stats -> fold BN2 into  z = fma(hq, c1q, c0)
__global__ __launch_bounds__(256) void r1_hreduce(
        const u32* __restrict__ hP, const u32* __restrict__ h2P,
        const float* __restrict__ g2, const float* __restrict__ b2,
        float* __restrict__ bn2c) {
    int j = blockIdx.x, tid = threadIdx.x;
    u32 s = 0; u64 s2 = 0;
    for (int k = tid; k < NPART; k += 256) { s += hP[j*NPART+k]; s2 += (u64)h2P[j*NPART+k]; }
    for (int off = 32; off; off >>= 1) { s += __shfl_down(s, off, 64); s2 += __shfl_down(s2, off, 64); }
    __shared__ u32 as_[4]; __shared__ u64 as2_[4];
    int lane = tid & 63, wave = tid >> 6;
    if (lane == 0) { as_[wave] = s; as2_[wave] = s2; }
    __syncthreads();
    if (tid == 0) {
        u32 S = as_[0] + as_[1] + as_[2] + as_[3];
        u64 S2 = as2_[0] + as2_[1] + as2_[2] + as2_[3];
        double m2 = (double)S * 0.25 / (double)BATCH;
        double e2 = (double)S2 * 0.0625 / (double)BATCH;
        double v2 = e2 - m2 * m2;
        float rs = (float)(1.0 / sqrt(v2 + 1e-5));
        float c1 = rs * g2[j];
        float c0 = fmaf(-(float)m2, c1, b2[j]);
        bn2c[j] = c1 * 0.25f; bn2c[128 + j] = c0;
    }
}

// K2: stage bits in LDS, recompute hq, softsign stats (dual f32 accumulators)
__global__ __launch_bounds__(256) void k2_sstats(
        const u64* __restrict__ xbits, const u64* __restrict__ wbits,
        const float* __restrict__ bn2c,
        float* __restrict__ sS, float* __restrict__ sS2) {
    __shared__ u64 lb[128][4];
    int tid = threadIdx.x;
    ((ulonglong2*)&lb[0][0])[tid] =
        ((const ulonglong2*)(xbits + (size_t)blockIdx.x * 512))[tid];
    __syncthreads();
    int j = tid & 127, half = tid >> 7;
    if (j >= DIM) return;
    u64 q0 = wbits[j*4+0], q1 = wbits[j*4+1], y0 = wbits[j*4+2], y1 = wbits[j*4+3];
    bool hasY = (y0 | y1) != 0;
    float c1q = bn2c[j], c0 = bn2c[128 + j];
    float SsA = 0.f, Ss2A = 0.f, SsB = 0.f, Ss2B = 0.f;
    int r0 = half * 64;
    for (int r = r0; r < r0 + 64; r += 2) {
        u64 z0 = lb[r][2], z1 = lb[r][3];
        u32 hqa = hq_from_bits(lb[r][0], lb[r][1], z0, z1,
                               q0, q1, y0, y1, hasY, (z0 | z1) != 0);
        u64 w0 = lb[r+1][2], w1 = lb[r+1][3];
        u32 hqb = hq_from_bits(lb[r+1][0], lb[r+1][1], w0, w1,
                               q0, q1, y0, y1, hasY, (w0 | w1) != 0);
        float za = fmaf((float)hqa, c1q, c0);
        float sa = za * __builtin_amdgcn_rcpf(1.f + fabsf(za));
        SsA += sa; Ss2A = fmaf(sa, sa, Ss2A);
        float zb = fmaf((float)hqb, c1q, c0);
        float sb = zb * __builtin_amdgcn_rcpf(1.f + fabsf(zb));
        SsB += sb; Ss2B = fmaf(sb, sb, Ss2B);
    }
    int pidx = j * NPART + blockIdx.x * 2 + half;
    sS[pidx] = SsA + SsB; sS2[pidx] = Ss2A + Ss2B;
}

// R2: reduce softsign stats (f64), fold BN1, derive the two integer
// thresholds per column; lin_w binarize computed inline.
__global__ __launch_bounds__(256) void r2_sreduce(
        const float* __restrict__ sS, const float* __restrict__ sS2,
        const float* __restrict__ g1, const float* __restrict__ b1,
        const float* __restrict__ bn2c, const float* __restrict__ lw,
        u32* __restrict__ meta) {
    int j = blockIdx.x, tid = threadIdx.x;
    double s = 0.0, s2 = 0.0;
    for (int k = tid; k < NPART; k += 256) { s += (double)sS[j*NPART+k]; s2 += (double)sS2[j*NPART+k]; }
    for (int off = 32; off; off >>= 1) { s += __shfl_down(s, off, 64); s2 += __shfl_down(s2, off, 64); }
    __shared__ double ds_[4], ds2_[4];
    __shared__ float sd1, sd0;
    __shared__ u32 cnt[3];
    __shared__ u32 sfirst, slast;
    int lane = tid & 63, wave = tid >> 6;
    if (lane == 0) { ds_[wave] = s; ds2_[wave] = s2; }
    if (tid < 3) cnt[tid] = 0;
    __syncthreads();
    if (tid == 0) {
        double S = ds_[0] + ds_[1] + ds_[2] + ds_[3];
        double S2 = ds2_[0] + ds2_[1] + ds2_[2] + ds2_[3];
        double m1 = S / (double)BATCH;
        double v1 = S2 / (double)BATCH - m1 * m1;
        float rs = (float)(1.0 / sqrt(v1 + 1e-5));
        float d1 = rs * g1[j];
        float d0 = fmaf(-(float)m1, d1, b1[j]);
        sd1 = d1; sd0 = d0;
    }
    __syncthreads();
    float c1q = bn2c[j], c0 = bn2c[128 + j];
    float d1 = sd1, d0 = sd0;
    for (int hq = tid; hq < 481; hq += 256) {
        float z = fmaf((float)hq, c1q, c0);
        float sv = z * __builtin_amdgcn_rcpf(1.f + fabsf(z));
        float h1 = fmaf(sv, d1, d0);
        u32 hb2 = h1 > 0.f ? 2u : (h1 == 0.f ? 1u : 0u);
        atomicAdd(&cnt[hb2], 1u);
        if (hq == 0)   sfirst = hb2;
        if (hq == 480) slast  = hb2;
    }
    __syncthreads();
    if (tid == 0) {
        u32 n0 = cnt[0], n1 = cnt[1], n2 = cnt[2];
        u32 dec = (slast < sfirst) ? 1u : 0u;
        u32 A = dec ? n2 : n0;
        u32 B = A + n1;
        float w0 = lw[j], w1 = lw[DIM + j];
        u32 l0 = w0 > 0.f ? 2u : (w0 == 0.f ? 1u : 0u);
        u32 l1 = w1 > 0.f ? 2u : (w1 == 0.f ? 1u : 0u);
        meta[2*j]   = A | (B << 9) | (dec << 18);
        meta[2*j+1] = l0 | (l1 << 16);
    }
}

// K3: thread <-> row, chunked-register column loop, per-block stat partials
// to distinct addresses (no global atomics).
__global__ __launch_bounds__(256) void k3_out(
        const u64* __restrict__ xbits, const u64* __restrict__ wbits,
        const u32* __restrict__ meta, const u32* __restrict__ oacc,
        u32* __restrict__ oqbuf, u32* __restrict__ oP) {
    __shared__ u64 sq0[DIM], sq1[DIM], smw[DIM], sy0[DIM], sy1[DIM];
    int tid = threadIdx.x;
    for (int k = tid; k < DIM; k += 256) {
        sq0[k] = wbits[k*4+0]; sq1[k] = wbits[k*4+1];
        sy0[k] = wbits[k*4+2]; sy1[k] = wbits[k*4+3];
        smw[k] = (u64)meta[2*k] | ((u64)meta[2*k+1] << 32);
    }
    __syncthreads();
    size_t row = (size_t)blockIdx.x * 256 + tid;
    const ulonglong2* xb = (const ulonglong2*)xbits;
    ulonglong2 rp = xb[row*2], rz = xb[row*2+1];
    u64 p0 = rp.x, p1 = rp.y, z0 = rz.x, z1 = rz.y;
    u32 oq = 0;
    for (int c = 0; c < DIM; c += CH) {
        ulonglong2 A[CH/2], B[CH/2], Mw[CH/2];
        #pragma unroll
        for (int t = 0; t < CH/2; ++t) {
            A[t] = *(const ulonglong2*)&sq0[c + 2*t];
            B[t] = *(const ulonglong2*)&sq1[c + 2*t];
            Mw[t] = *(const ulonglong2*)&smw[c + 2*t];
        }
        #pragma unroll
        for (int t = 0; t < CH/2; ++t) {
            proc_col(p0, p1, A[t].x, B[t].x, Mw[t].x, oq);
            proc_col(p0, p1, A[t].y, B[t].y, Mw[t].y, oq);
        }
    }
    bool slow = (oacc[8] != 0) | ((z0 | z1) != 0);
    if (__any(slow)) {
        if (slow) {          // exact full recompute (expected ~2 rows/batch)
            oq = 0;
            for (int j = 0; j < DIM; ++j) {
                u64 y0 = sy0[j], y1 = sy1[j];
                u32 hq = hq_from_bits(p0, p1, z0, z1, sq0[j], sq1[j], y0, y1,
                                      (y0 | y1) != 0, (z0 | z1) != 0);
                u64 mw = smw[j];
                u32 m = (u32)mw, lw = (u32)(mw >> 32);
                u32 ge = (u32)(hq >= (m & 511u)) + (u32)(hq >= ((m >> 9) & 511u));
                oq += ((m & (1u << 18)) ? 2u - ge : ge) * lw;
            }
        }
    }
    oqbuf[row] = oq;
    u32 o0 = oq & 0xffffu, o1 = oq >> 16;
    u32 a = o0, b = o1, c2 = o0 * o0, d2 = o1 * o1;
    for (int off = 32; off; off >>= 1) {
        a += __shfl_down(a, off, 64);  b += __shfl_down(b, off, 64);
        c2 += __shfl_down(c2, off, 64); d2 += __shfl_down(d2, off, 64);
    }
    __shared__ u32 r0_[4], r1_[4], r2_[4], r3_[4];
    int lane = tid & 63, wv = tid >> 6;
    if (lane == 0) { r0_[wv] = a; r1_[wv] = b; r2_[wv] = c2; r3_[wv] = d2; }
    __syncthreads();
    if (tid == 0) {
        u32* dst = oP + (size_t)blockIdx.x * 4;
        dst[0] = r0_[0] + r0_[1] + r0_[2] + r0_[3];
        dst[1] = r1_[0] + r1_[1] + r1_[2] + r1_[3];
        dst[2] = r2_[0] + r2_[1] + r2_[2] + r2_[3];
        dst[3] = r3_[0] + r3_[1] + r3_[2] + r3_[3];
    }
}

// K4: each block redundantly reduces the 16KB oP partials (exact integers,
// f64 finalize), then normalizes its 256 rows + 2-class log_softmax.
__global__ __launch_bounds__(256) void k4_final(
        const u32* __restrict__ oqbuf, const u32* __restrict__ oP,
        float* __restrict__ out) {
    int tid = threadIdx.x;
    u64 a = 0, b = 0, c2 = 0, d2 = 0;
    for (int k = tid; k < NBLK3; k += 256) {
        uint4 p = ((const uint4*)oP)[k];
        a += p.x; b += p.y; c2 += p.z; d2 += p.w;
    }
    for (int off = 32; off; off >>= 1) {
        a += __shfl_down(a, off, 64);  b += __shfl_down(b, off, 64);
        c2 += __shfl_down(c2, off, 64); d2 += __shfl_down(d2, off, 64);
    }
    __shared__ u64 s0_[4], s1_[4], s2_[4], s3_[4];
    __shared__ float sfin[4];
    int lane = tid & 63, wv = tid >> 6;
    if (lane == 0) { s0_[wv] = a; s1_[wv] = b; s2_[wv] = c2; s3_[wv] = d2; }
    __syncthreads();
    if (tid < 2) {
        u64 S  = (tid == 0) ? s0_[0]+s0_[1]+s0_[2]+s0_[3] : s1_[0]+s1_[1]+s1_[2]+s1_[3];
        u64 S2 = (tid == 0) ? s2_[0]+s2_[1]+s2_[2]+s2_[3] : s3_[0]+s3_[1]+s3_[2]+s3_[3];
        double av = (double)S * 0.25 / (double)BATCH;
        double e2 = (double)S2 * 0.0625 / (double)BATCH;
        double vo = e2 - av * av;
        sfin[tid]     = (float)av;
        sfin[2 + tid] = (float)(1.0 / sqrt(vo + 1e-5));
    }
    __syncthreads();
    size_t row = (size_t)blockIdx.x * 256 + tid;
    u32 v = oqbuf[row];
    float o0 = ((float)(v & 0xffffu) * 0.25f - sfin[0]) * sfin[2];
    float o1 = ((float)(v >> 16)     * 0.25f - sfin[1]) * sfin[3];
    float m = fmaxf(o0, o1);
    float l0 = o0 - m, l1 = o1 - m;
    float ls = logf(expf(l0) + expf(l1));
    ((float2*)out)[row] = make_float2(l0 - ls, l1 - ls);
}

extern "C" void kernel_launch(void* const* d_in, const int* in_sizes, int n_in,
                              void* d_out, int out_size, void* d_ws, size_t ws_size,
                              hipStream_t stream) {
    const float* x  = (const float*)d_in[0];
    const float* cw = (const float*)d_in[1];
    const float* g2 = (const float*)d_in[2];
    const float* b2 = (const float*)d_in[3];
    const float* g1 = (const float*)d_in[4];
    const float* b1 = (const float*)d_in[5];
    const float* lw = (const float*)d_in[6];
    // d_in[7] (lin_b) cancels through the final no-affine batchnorm
    float* out = (float*)d_out;
    if (ws_size < (size_t)WS_TOTAL) return;   // fail loudly via poisoned d_out

    char* ws = (char*)d_ws;
    u64* xbits = (u64*)(ws + WS_XBITS);
    u64* wbits = (u64*)(ws + WS_WBITS);
    u32* meta  = (u32*)(ws + WS_META);
    u32* hP    = (u32*)(ws + WS_HS);
    u32* h2P   = (u32*)(ws + WS_HS2);
    float* sP  = (float*)(ws + WS_SS);
    float* s2P = (float*)(ws + WS_SS2);
    float* bn2c = (float*)(ws + WS_BN2C);
    u32* oqbuf = (u32*)(ws + WS_OQ);
    u32* oacc  = (u32*)(ws + WS_OACC);
    u32* oP    = (u32*)(ws + WS_OP);

    k1_pack_hstats<<<NBLK1, 256, 0, stream>>>(x, cw, wbits, oacc, xbits, hP, h2P);
    r1_hreduce    <<<DIM, 256, 0, stream>>>(hP, h2P, g2, b2, bn2c);
    k2_sstats     <<<NBLK1, 256, 0, stream>>>(xbits, wbits, bn2c, sP, s2P);
    r2_sreduce    <<<DIM, 256, 0, stream>>>(sP, s2P, g1, b1, bn2c, lw, meta);
    k3_out        <<<NBLK3, 256, 0, stream>>>(xbits, wbits, meta, oacc, oqbuf, oP);
    k4_final      <<<NBLK3, 256, 0, stream>>>(oqbuf, oP, out);
}